// Round 9
// baseline (601.224 us; speedup 1.0000x reference)
//
#include <hip/hip_runtime.h>
#include <cstdint>

// ---------------------------------------------------------------------------
// DirGraphSAGE round 17: barrier-free direct-fragment GEMM.
//  r16 accounting: gemm ~30us/layer vs ~1.2us of actual MFMA pipe time.
//  Cost = 12 kc-chunks x 2 barriers + LDS round-trip per chunk, with zero
//  cross-wave reuse of sA (each wave reads back only the rows it staged) and
//  W being L2-resident anyway. k_gemm2 loads A/W fragments DIRECTLY from
//  global to registers at the provably-identical addresses the LDS path
//  delivered: A-frag spans 4KB contiguous per wave; W-frags are L2 hits.
//  No LDS, no __syncthreads in the K-loop -> compiler pipelines freely.
//  Bit-identical fragments + MFMA order -> absmax unchanged.
//  Everything else byte-identical to r16 (front fusion, rec fill, bucket-
//  sorted ep layout, flat x4 agg).
// ---------------------------------------------------------------------------

typedef __bf16 bf16x8 __attribute__((ext_vector_type(8)));
typedef float f32x4 __attribute__((ext_vector_type(4)));

__device__ __forceinline__ unsigned short f2bf(float f) {
  unsigned u = __float_as_uint(f);
  u += 0x7FFFu + ((u >> 16) & 1u);   // round-to-nearest-even
  return (unsigned short)(u >> 16);
}
__device__ __forceinline__ float bflo(unsigned u) { return __uint_as_float(u << 16); }
__device__ __forceinline__ float bfhi(unsigned u) { return __uint_as_float(u & 0xFFFF0000u); }

__device__ __forceinline__ bf16x8 as_bf16x8(uint4 u) {
  union { uint4 u4; bf16x8 b8; } cv; cv.u4 = u; return cv.b8;
}

// prefix for bucket b (0..7) from packed words p12,p34,p56,p7; p0 = 0.
__device__ __forceinline__ unsigned pre8(unsigned a, unsigned b, unsigned c,
                                         unsigned d, int bk) {
  if (bk == 0) return 0u;
  int k = bk - 1;  // 0..6
  unsigned w = (k < 2) ? a : (k < 4) ? b : (k < 6) ? c : d;
  return (k & 1) ? (w >> 16) : (w & 0xFFFFu);
}

// Fused front kernel, 3 roles by blockIdx:
//  role E (blk%3==0, blk<3*edgeBlocks): per-(node,bucket) rank atomics
//  role C (other blk < wBase): x -> bf16 row-major xbu
//  role W (blk >= wBase): W -> Wt_hi/Wt_lo transposed split-bf16
__global__ __launch_bounds__(256) void k_front(const int* __restrict__ src,
                                               const int* __restrict__ dst,
                                               int* __restrict__ cin_p,
                                               int* __restrict__ cout_p,
                                               unsigned* __restrict__ rank_pk,
                                               int E, int wBase,
                                               const float* __restrict__ x,
                                               unsigned* __restrict__ xbu, int n,
                                               const float* __restrict__ Wa,
                                               const float* __restrict__ Wb,
                                               const float* __restrict__ Wc,
                                               unsigned* __restrict__ Ha,
                                               unsigned* __restrict__ Hb,
                                               unsigned* __restrict__ Hc,
                                               unsigned* __restrict__ La,
                                               unsigned* __restrict__ Lb,
                                               unsigned* __restrict__ Lc) {
  int blk = blockIdx.x;
  if (blk >= wBase) {          // W-conv role: 288 blocks (3 x 96)
    int wblk = blk - wBase;
    int y = wblk / 96;
    int t = (wblk - y * 96) * 256 + threadIdx.x;
    if (t >= 128 * 192) return;
    const float* W = (y == 0) ? Wa : ((y == 1) ? Wb : Wc);
    unsigned* Wth = (y == 0) ? Ha : ((y == 1) ? Hb : Hc);
    unsigned* Wtl = (y == 0) ? La : ((y == 1) ? Lb : Lc);
    int j = t / 192, k2 = t - j * 192;
    int k = k2 * 2;
    float w0 = W[k * 128 + j], w1 = W[(k + 1) * 128 + j];
    unsigned short h0 = f2bf(w0), h1 = f2bf(w1);
    float l0 = w0 - __uint_as_float((unsigned)h0 << 16);
    float l1 = w1 - __uint_as_float((unsigned)h1 << 16);
    Wth[t] = (unsigned)h0 | ((unsigned)h1 << 16);
    Wtl[t] = (unsigned)f2bf(l0) | ((unsigned)f2bf(l1) << 16);
  } else if (blk % 3 == 0) {   // edge role
    int e = (blk / 3) * 256 + threadIdx.x;
    if (e >= E) return;
    int s = src[e], d = dst[e];
    int bf = (unsigned)s >> 13;   // bucket of gathered row for fwd list (by dst)
    int bb = (unsigned)d >> 13;   // bucket of gathered row for bwd list (by src)
    unsigned rf = (unsigned)atomicAdd(&cin_p[(size_t)d * 16 + bf], 1);
    unsigned rb = (unsigned)atomicAdd(&cout_p[(size_t)s * 16 + bb], 1);
    rank_pk[e] = (rf & 0xFFFFu) | (rb << 16);
  } else {                     // conv role
    int cb = blk - blk / 3 - 1;
    int idx = cb * 256 + threadIdx.x;  // over n*32 float4s
    if (idx >= n * 32) return;
    float4 xv = ((const float4*)x)[idx];
    unsigned u0 = (unsigned)f2bf(xv.x) | ((unsigned)f2bf(xv.y) << 16);
    unsigned u1 = (unsigned)f2bf(xv.z) | ((unsigned)f2bf(xv.w) << 16);
    ((uint2*)xbu)[idx] = make_uint2(u0, u1);
  }
}

// Compact + scan-partials + rec deg/prefix fields.
// rec line (16 u32): [0]=offf [1]=degs [2..5]=basef p12,p34,p56,p7 [6,7]=pad
//                    [8]=offb [9]=degs [10..13]=baseb [14,15]=pad
__global__ __launch_bounds__(256) void k_compact_part(const int* __restrict__ cin_p,
                                                      const int* __restrict__ cout_p,
                                                      int* __restrict__ cin_d,
                                                      int* __restrict__ cout_d,
                                                      unsigned* __restrict__ rec,
                                                      int* __restrict__ partA,
                                                      int* __restrict__ partB, int n) {
  __shared__ int redA[256], redB[256];
  int t = threadIdx.x;
  int base = blockIdx.x * 2048 + t * 8;
  int sA = 0, sB = 0;
#pragma unroll
  for (int k = 0; k < 8; ++k) {
    int i = base + k;
    if (i < n) {
      unsigned cinv, coutv;
      unsigned f12, f34, f56, f7;
      {
        const int* pf = &cin_p[(size_t)i * 16];
        int c0 = pf[0], c1 = pf[1], c2 = pf[2], c3 = pf[3];
        int c4 = pf[4], c5 = pf[5], c6 = pf[6], c7 = pf[7];
        unsigned run = c0;
        unsigned p1 = run; run += c1; unsigned p2 = run; run += c2;
        unsigned p3 = run; run += c3; unsigned p4 = run; run += c4;
        unsigned p5 = run; run += c5; unsigned p6 = run; run += c6;
        unsigned p7 = run; run += c7;
        cin_d[i] = (int)run;
        sA += (int)run;
        cinv = (run > 65535u) ? 65535u : run;
        f12 = p1 | (p2 << 16); f34 = p3 | (p4 << 16);
        f56 = p5 | (p6 << 16); f7 = p7;
      }
      unsigned b12, b34, b56, b7;
      {
        const int* pf = &cout_p[(size_t)i * 16];
        int c0 = pf[0], c1 = pf[1], c2 = pf[2], c3 = pf[3];
        int c4 = pf[4], c5 = pf[5], c6 = pf[6], c7 = pf[7];
        unsigned run = c0;
        unsigned p1 = run; run += c1; unsigned p2 = run; run += c2;
        unsigned p3 = run; run += c3; unsigned p4 = run; run += c4;
        unsigned p5 = run; run += c5; unsigned p6 = run; run += c6;
        unsigned p7 = run; run += c7;
        cout_d[i] = (int)run;
        sB += (int)run;
        coutv = (run > 65535u) ? 65535u : run;
        b12 = p1 | (p2 << 16); b34 = p3 | (p4 << 16);
        b56 = p5 | (p6 << 16); b7 = p7;
      }
      unsigned degs = cinv | (coutv << 16);
      unsigned* r = &rec[(size_t)i * 16];
      r[1] = degs; r[2] = f12; r[3] = f34; r[4] = f56; r[5] = f7;
      r[9] = degs; r[10] = b12; r[11] = b34; r[12] = b56; r[13] = b7;
    }
  }
  redA[t] = sA; redB[t] = sB;
  __syncthreads();
  for (int o = 128; o > 0; o >>= 1) {
    if (t < o) { redA[t] += redA[t + o]; redB[t] += redB[t + o]; }
    __syncthreads();
  }
  if (t == 0) { partA[blockIdx.x] = redA[0]; partB[blockIdx.x] = redB[0]; }
}

__global__ __launch_bounds__(64) void k_scan_tops(int* __restrict__ partA,
                                                  int* __restrict__ partB, int nb) {
  int* part = blockIdx.y ? partB : partA;
  if (threadIdx.x == 0) {
    int run = 0;
    for (int i = 0; i < nb; ++i) { int v = part[i]; part[i] = run; run += v; }
  }
}

// Scan output: dense off arrays (for agg) + off fields in rec (for fill).
__global__ __launch_bounds__(256) void k_scan_out(const int* __restrict__ cntA,
                                                  const int* __restrict__ cntB,
                                                  const int* __restrict__ partA,
                                                  const int* __restrict__ partB,
                                                  int* __restrict__ offA,
                                                  int* __restrict__ offB,
                                                  unsigned* __restrict__ rec, int n) {
  const int* cnt = blockIdx.y ? cntB : cntA;
  const int* part = blockIdx.y ? partB : partA;
  int* off = blockIdx.y ? offB : offA;
  int fld = blockIdx.y ? 8 : 0;   // rec word for this direction's off
  __shared__ int ts[256];
  int t = threadIdx.x;
  int base = blockIdx.x * 2048 + t * 8;
  int v[8];
  int s = 0;
#pragma unroll
  for (int i = 0; i < 8; ++i) {
    int idx = base + i;
    int c = (idx < n) ? cnt[idx] : 0;
    v[i] = s;          // exclusive prefix within thread
    s += c;
  }
  ts[t] = s;
  __syncthreads();
  for (int o = 1; o < 256; o <<= 1) {
    int val = (t >= o) ? ts[t - o] : 0;
    __syncthreads();
    ts[t] += val;
    __syncthreads();
  }
  int blockbase = part[blockIdx.x] + (t ? ts[t - 1] : 0);
#pragma unroll
  for (int i = 0; i < 8; ++i) {
    int idx = base + i;
    if (idx <= n) {
      int val = blockbase + v[i];
      off[idx] = val;   // idx==n writes the total
      if (idx < n) rec[(size_t)idx * 16 + fld] = (unsigned)val;
    }
  }
}

// Atomic-free fill; 2 random 64B line touches per edge (rec[d], rec[s]).
__global__ __launch_bounds__(256) void k_fill(const int* __restrict__ src,
                                              const int* __restrict__ dst,
                                              const unsigned* __restrict__ rank_pk,
                                              const uint4* __restrict__ rec4,
                                              unsigned* __restrict__ epf,
                                              unsigned* __restrict__ epb, int E) {
  int e = blockIdx.x * 256 + threadIdx.x;
  if (e >= E) return;
  int s = src[e], d = dst[e];
  unsigned rp = rank_pk[e];
  int rf = (int)(rp & 0xFFFFu), rb = (int)(rp >> 16);
  int bf = (unsigned)s >> 13, bb = (unsigned)d >> 13;
  // F-half of d: slot0 = (offf, degs, p12, p34), slot1 = (p56, p7, -, -)
  uint4 f0 = rec4[(size_t)d * 4 + 0];
  uint4 f1 = rec4[(size_t)d * 4 + 1];
  // B-half of s: slot2 = (offb, degs, p12, p34), slot3 = (p56, p7, -, -)
  uint4 b0 = rec4[(size_t)s * 4 + 2];
  uint4 b1 = rec4[(size_t)s * 4 + 3];
  unsigned co = b0.y >> 16;       // cout of s (fwd weight deg)
  unsigned ci = f0.y & 0xFFFFu;   // cin of d (bwd weight deg)
  unsigned pf = pre8(f0.z, f0.w, f1.x, f1.y, bf);
  unsigned pb = pre8(b0.z, b0.w, b1.x, b1.y, bb);
  epf[f0.x + pf + (unsigned)rf] = ((unsigned)s << 16) | co;
  epb[b0.x + pb + (unsigned)rb] = ((unsigned)d << 16) | ci;
}

// Single-pass row-major aggregation (r11's flat kernel). 16 lanes/node,
// 4 nodes/wave, x4 unroll. Edge lists are bucket-major (sorted by gathered-id
// slab): all concurrent waves walk x-slabs 0..7 monotonically -> the active
// slab tends to stay L2-resident without any barriers or loop overhead.
__global__ __launch_bounds__(256) void k_agg6(const uint4* __restrict__ xb,
                                              const int* __restrict__ offA,
                                              const unsigned* __restrict__ epA,
                                              const int* __restrict__ offB,
                                              const unsigned* __restrict__ epB,
                                              uint4* __restrict__ outA,
                                              uint4* __restrict__ outB, int n) {
  int lane = threadIdx.x & 63;
  int gi = lane >> 4, c = lane & 15;     // node-in-wave, uint4 column
  int node = ((blockIdx.x * 256 + threadIdx.x) >> 6) * 4 + gi;
  if (node >= n) return;
  const int* off = blockIdx.y ? offB : offA;
  const unsigned* ep = blockIdx.y ? epB : epA;
  uint4* out = blockIdx.y ? outB : outA;

  int i = off[node], end = off[node + 1];
  float acc[8];
#pragma unroll
  for (int k = 0; k < 8; ++k) acc[k] = 0.f;

#define AGG_BODY(r_, w_)                                                      \
  acc[0] = fmaf(bflo(r_.x), w_, acc[0]); acc[1] = fmaf(bfhi(r_.x), w_, acc[1]); \
  acc[2] = fmaf(bflo(r_.y), w_, acc[2]); acc[3] = fmaf(bfhi(r_.y), w_, acc[3]); \
  acc[4] = fmaf(bflo(r_.z), w_, acc[4]); acc[5] = fmaf(bfhi(r_.z), w_, acc[5]); \
  acc[6] = fmaf(bflo(r_.w), w_, acc[6]); acc[7] = fmaf(bfhi(r_.w), w_, acc[7]);

  for (; i + 3 < end; i += 4) {
    unsigned e0 = ep[i], e1 = ep[i + 1], e2 = ep[i + 2], e3 = ep[i + 3];
    uint4 r0 = xb[(size_t)(e0 >> 16) * 16 + c];
    uint4 r1 = xb[(size_t)(e1 >> 16) * 16 + c];
    uint4 r2 = xb[(size_t)(e2 >> 16) * 16 + c];
    uint4 r3 = xb[(size_t)(e3 >> 16) * 16 + c];
    float w0 = 1.0f / (float)(e0 & 0xFFFFu);   // IEEE div: bit-exact vs table
    float w1 = 1.0f / (float)(e1 & 0xFFFFu);
    float w2 = 1.0f / (float)(e2 & 0xFFFFu);
    float w3 = 1.0f / (float)(e3 & 0xFFFFu);
    AGG_BODY(r0, w0)
    AGG_BODY(r1, w1)
    AGG_BODY(r2, w2)
    AGG_BODY(r3, w3)
  }
  for (; i < end; ++i) {
    unsigned e0 = ep[i];
    uint4 r0 = xb[(size_t)(e0 >> 16) * 16 + c];
    float w0 = 1.0f / (float)(e0 & 0xFFFFu);
    AGG_BODY(r0, w0)
  }
#undef AGG_BODY

  uint4 o;
  o.x = (unsigned)f2bf(acc[0]) | ((unsigned)f2bf(acc[1]) << 16);
  o.y = (unsigned)f2bf(acc[2]) | ((unsigned)f2bf(acc[3]) << 16);
  o.z = (unsigned)f2bf(acc[4]) | ((unsigned)f2bf(acc[5]) << 16);
  o.w = (unsigned)f2bf(acc[6]) | ((unsigned)f2bf(acc[7]) << 16);
  out[(size_t)node * 16 + c] = o;
}

// Barrier-free MFMA GEMM: direct-to-register fragment loads (no LDS).
// Fragments are byte-identical to the r16 LDS path:
//  A-frag(mt): src4[(bm0+(2w+mt)*16+(lane&15))*16 + ko + (lane>>4)]
//  W-frag(nt): Wh4/Wl4[(nt*16+(lane&15))*48 + kc*4 + (lane>>4)]
// If outb: write bf16(relu(h)) row-major (next layer's xbu). Else fp32 outf.
__global__ __launch_bounds__(256) void k_gemm(const unsigned* __restrict__ xbu,
                                              const unsigned* __restrict__ fwdb,
                                              const unsigned* __restrict__ bwdb,
                                              const unsigned* __restrict__ Wth,
                                              const unsigned* __restrict__ Wtl,
                                              const float* __restrict__ bias,
                                              unsigned short* __restrict__ outb,
                                              float* __restrict__ outf, int n) {
  int tid = threadIdx.x;
  int bm0 = blockIdx.x * 128;
  int w = tid >> 6, lane = tid & 63;
  int lr = lane & 15, q = lane >> 4;   // frag row-in-tile, k-quad

  f32x4 acc[2][8];
#pragma unroll
  for (int mt = 0; mt < 2; ++mt)
#pragma unroll
    for (int nt = 0; nt < 8; ++nt) acc[mt][nt] = (f32x4){0.f, 0.f, 0.f, 0.f};

  const uint4* Wh4 = (const uint4*)Wth;   // row j: 48 uint4 (384 bf16)
  const uint4* Wl4 = (const uint4*)Wtl;
  const uint4 zero4 = make_uint4(0u, 0u, 0u, 0u);

  int vr0 = bm0 + (2 * w + 0) * 16 + lr;
  int vr1 = bm0 + (2 * w + 1) * 16 + lr;
  bool ok0 = vr0 < n, ok1 = vr1 < n;

  for (int kc = 0; kc < 12; ++kc) {
    const uint4* src4 = (const uint4*)((kc < 4) ? xbu : ((kc < 8) ? fwdb : bwdb));
    int ko = (kc & 3) * 4;   // uint4 offset within row (16 uint4 = 128 bf16)
    uint4 a0u = ok0 ? src4[(size_t)vr0 * 16 + ko + q] : zero4;
    uint4 a1u = ok1 ? src4[(size_t)vr1 * 16 + ko + q] : zero4;
    bf16x8 a0 = as_bf16x8(a0u);
    bf16x8 a1 = as_bf16x8(a1u);
#pragma unroll
    for (int nt = 0; nt < 8; ++nt) {
      size_t wi = (size_t)(nt * 16 + lr) * 48 + kc * 4 + q;
      bf16x8 bh = as_bf16x8(Wh4[wi]);
      bf16x8 bl = as_bf16x8(Wl4[wi]);
      acc[0][nt] = __builtin_amdgcn_mfma_f32_16x16x32_bf16(a0, bh, acc[0][nt], 0, 0, 0);
      acc[0][nt] = __builtin_amdgcn_mfma_f32_16x16x32_bf16(a0, bl, acc[0][nt], 0, 0, 0);
      acc[1][nt] = __builtin_amdgcn_mfma_f32_16x16x32_bf16(a1, bh, acc[1][nt], 0, 0, 0);
      acc[1][nt] = __builtin_amdgcn_mfma_f32_16x16x32_bf16(a1, bl, acc[1][nt], 0, 0, 0);
    }
  }

  // Epilogue. C layout: col = lane&15, row = (lane>>4)*4 + reg  (m89-verified)
  int col = lane & 15;
  float bv[8];
#pragma unroll
  for (int nt = 0; nt < 8; ++nt) bv[nt] = bias[nt * 16 + col];
#pragma unroll
  for (int mt = 0; mt < 2; ++mt) {
    int rowbase = bm0 + w * 32 + mt * 16 + (lane >> 4) * 4;
#pragma unroll
    for (int reg = 0; reg < 4; ++reg) {
      int row = rowbase + reg;
      if (row >= n) continue;
      if (outb) {
#pragma unroll
        for (int nt = 0; nt < 8; ++nt) {
          float t = fmaxf(acc[mt][nt][reg] + bv[nt], 0.f);   // relu layers
          outb[(size_t)row * 128 + nt * 16 + col] = f2bf(t);
        }
      } else {
#pragma unroll
        for (int nt = 0; nt < 8; ++nt) {
          float t = acc[mt][nt][reg] + bv[nt];
          outf[(size_t)row * 128 + nt * 16 + col] = t;
        }
      }
    }
  }
}

extern "C" void kernel_launch(void* const* d_in, const int* in_sizes, int n_in,
                              void* d_out, int out_size, void* d_ws, size_t ws_size,
                              hipStream_t stream) {
  const int D = 128;
  const int N = in_sizes[0] / D;
  const int E = in_sizes[7];

  const float* x  = (const float*)d_in[0];
  const float* W0 = (const float*)d_in[1];
  const float* b0 = (const float*)d_in[2];
  const float* W1 = (const float*)d_in[3];
  const float* b1 = (const float*)d_in[4];
  const float* W2 = (const float*)d_in[5];
  const float* b2 = (const float*)d_in[6];
  const int* src  = (const int*)d_in[7];
  const int* dst  = (const int*)d_in[8];
  float* out = (float*)d_out;

  char* p = (char*)d_ws;
  auto alloc = [&](size_t bytes) -> char* {
    char* r = p;
    p += (bytes + 15) & ~(size_t)15;
    return r;
  };
  int* cin_p  = (int*)alloc((size_t)N * 64);   // padded: 8 bucket slots / 64B line
  int* cout_p = (int*)alloc((size_t)N * 64);
  int* cin_d  = (int*)alloc((size_t)N * 4);    // dense totals for scan
  int* cout_d = (int*)alloc((size_t)N * 4);
  int* offf = (int*)alloc((size_t)(N + 1) * 4);
  int* offb = (int*)alloc((size_t)(N + 1) * 4);
  unsigned* rec = (unsigned*)alloc((size_t)N * 64);  // 64B fill record / node
  unsigned* rank_pk = (unsigned*)alloc((size_t)E * 4);   // rankf | rankb<<16
  unsigned* epf = (unsigned*)alloc((size_t)E * 4);       // (u<<16 | deg) payload
  unsigned* epb = (unsigned*)alloc((size_t)E * 4);
  unsigned* xbu = (unsigned*)alloc((size_t)N * 64 * 4);  // row-major bf16x2
  unsigned* fwdb = (unsigned*)alloc((size_t)N * 64 * 4);
  unsigned* bwdb = (unsigned*)alloc((size_t)N * 64 * 4);
  unsigned* Wth[3], *Wtl[3];
  for (int l = 0; l < 3; ++l) {
    Wth[l] = (unsigned*)alloc((size_t)128 * 192 * 4);
    Wtl[l] = (unsigned*)alloc((size_t)128 * 192 * 4);
  }
  int nbScan = (N + 1 + 2047) / 2048;
  int* partA = (int*)alloc((size_t)(nbScan + 1) * 4);
  int* partB = (int*)alloc((size_t)(nbScan + 1) * 4);

  hipMemsetAsync(cin_p, 0, (size_t)2 * N * 64, stream);  // cin_p+cout_p contiguous

  int edgeBlocks = (E + 255) / 256;
  int convBlocks = (N * 32 + 255) / 256;
  int wBase = edgeBlocks + convBlocks + 2;   // edge+conv interleave region
  int fusedBlocks = wBase + 288;             // + 3x96 wconv blocks
  k_front<<<fusedBlocks, 256, 0, stream>>>(src, dst, cin_p, cout_p, rank_pk,
                                           E, wBase, x, xbu, N,
                                           W0, W1, W2,
                                           Wth[0], Wth[1], Wth[2],
                                           Wtl[0], Wtl[1], Wtl[2]);
  k_compact_part<<<nbScan, 256, 0, stream>>>(cin_p, cout_p, cin_d, cout_d,
                                             rec, partA, partB, N);
  k_scan_tops<<<dim3(1, 2), 64, 0, stream>>>(partA, partB, nbScan);
  k_scan_out<<<dim3(nbScan, 2), 256, 0, stream>>>(cin_d, cout_d, partA, partB,
                                                  offf, offb, rec, N);
  k_fill<<<(E + 255) / 256, 256, 0, stream>>>(src, dst, rank_pk,
                                              (const uint4*)rec, epf, epb, E);

  const float* bs[3] = {b0, b1, b2};
  int aggBlocks = (N + 15) / 16;          // 16 nodes/block (4 waves); dir = y
  int gemmBlocks = (N + 127) / 128;

  for (int l = 0; l < 3; ++l) {
    k_agg6<<<dim3(aggBlocks, 2), 256, 0, stream>>>(
        (const uint4*)xbu, offf, epf, offb, epb,
        (uint4*)fwdb, (uint4*)bwdb, N);
    if (l < 2) {
      k_gemm<<<gemmBlocks, 256, 0, stream>>>(xbu, fwdb, bwdb, Wth[l], Wtl[l],
                                             bs[l], (unsigned short*)xbu, nullptr, N);
    } else {
      k_gemm<<<gemmBlocks, 256, 0, stream>>>(xbu, fwdb, bwdb, Wth[l], Wtl[l],
                                             bs[l], nullptr, out, N);
    }
  }
}

// Round 10
// 511.896 us; speedup vs baseline: 1.1745x; 1.1745x over previous
//
#include <hip/hip_runtime.h>
#include <cstdint>

// ---------------------------------------------------------------------------
// DirGraphSAGE round 18: fragment-major W + barrier-free direct GEMM.
//  r17 post-mortem: direct GEMM was issue-bound, NOT BW-bound (FETCH 20MB,
//  MfmaUtil 4.9%): W-frag loads at lane-stride 768B fragmented into ~64 L2
//  transactions per instruction (192 instrs/K-loop). Fix = store W in
//  FRAGMENT-MAJOR order Wfrag[kc][nt][lane] so every W-load is 64 lanes x
//  16B consecutive = one coalesced 1KB L2 hit. Values per (kc,nt,lane) are
//  bit-identical to the r16/r17 fragments (same f2bf rounding, same MFMA
//  order) -> absmax unchanged.
//  k_front W-role rewritten to emit the frag-major layout (72 blocks).
//  Everything else byte-identical to r17 (front fusion, rec fill, bucket-
//  sorted ep layout, flat x4 agg).
// ---------------------------------------------------------------------------

typedef __bf16 bf16x8 __attribute__((ext_vector_type(8)));
typedef float f32x4 __attribute__((ext_vector_type(4)));

__device__ __forceinline__ unsigned short f2bf(float f) {
  unsigned u = __float_as_uint(f);
  u += 0x7FFFu + ((u >> 16) & 1u);   // round-to-nearest-even
  return (unsigned short)(u >> 16);
}
__device__ __forceinline__ float bflo(unsigned u) { return __uint_as_float(u << 16); }
__device__ __forceinline__ float bfhi(unsigned u) { return __uint_as_float(u & 0xFFFF0000u); }

__device__ __forceinline__ bf16x8 as_bf16x8(uint4 u) {
  union { uint4 u4; bf16x8 b8; } cv; cv.u4 = u; return cv.b8;
}

// prefix for bucket b (0..7) from packed words p12,p34,p56,p7; p0 = 0.
__device__ __forceinline__ unsigned pre8(unsigned a, unsigned b, unsigned c,
                                         unsigned d, int bk) {
  if (bk == 0) return 0u;
  int k = bk - 1;  // 0..6
  unsigned w = (k < 2) ? a : (k < 4) ? b : (k < 6) ? c : d;
  return (k & 1) ? (w >> 16) : (w & 0xFFFFu);
}

// Fused front kernel, 3 roles by blockIdx:
//  role E (blk%3==0, blk<3*edgeBlocks): per-(node,bucket) rank atomics
//  role C (other blk < wBase): x -> bf16 row-major xbu
//  role W (blk >= wBase): W -> fragment-major split-bf16 Wfrag[kc][nt][lane]
//    value: 8 bf16 of W[ks..ks+7][j], j = nt*16+(lane&15), ks = (kc*4+lane>>4)*8
__global__ __launch_bounds__(256) void k_front(const int* __restrict__ src,
                                               const int* __restrict__ dst,
                                               int* __restrict__ cin_p,
                                               int* __restrict__ cout_p,
                                               unsigned* __restrict__ rank_pk,
                                               int E, int wBase,
                                               const float* __restrict__ x,
                                               unsigned* __restrict__ xbu, int n,
                                               const float* __restrict__ Wa,
                                               const float* __restrict__ Wb,
                                               const float* __restrict__ Wc,
                                               uint4* __restrict__ Ha,
                                               uint4* __restrict__ Hb,
                                               uint4* __restrict__ Hc,
                                               uint4* __restrict__ La,
                                               uint4* __restrict__ Lb,
                                               uint4* __restrict__ Lc) {
  int blk = blockIdx.x;
  if (blk >= wBase) {          // W-conv role: 72 blocks (3 x 24)
    int wblk = blk - wBase;
    int y = wblk / 24;
    int t = (wblk - y * 24) * 256 + threadIdx.x;   // 0..6143 per matrix
    if (t >= 12 * 8 * 64) return;
    const float* W = (y == 0) ? Wa : ((y == 1) ? Wb : Wc);
    uint4* Hf = (y == 0) ? Ha : ((y == 1) ? Hb : Hc);
    uint4* Lf = (y == 0) ? La : ((y == 1) ? Lb : Lc);
    int kc = t >> 9;            // /512
    int rem = t & 511;
    int nt = rem >> 6;
    int lane = rem & 63;
    int q = lane >> 4, lr = lane & 15;
    int j = nt * 16 + lr;
    int ks = (kc * 4 + q) * 8;
    unsigned hu[4], lu[4];
#pragma unroll
    for (int m = 0; m < 4; ++m) {
      float w0 = W[(size_t)(ks + 2 * m) * 128 + j];
      float w1 = W[(size_t)(ks + 2 * m + 1) * 128 + j];
      unsigned short h0 = f2bf(w0), h1 = f2bf(w1);
      float l0 = w0 - __uint_as_float((unsigned)h0 << 16);
      float l1 = w1 - __uint_as_float((unsigned)h1 << 16);
      hu[m] = (unsigned)h0 | ((unsigned)h1 << 16);
      lu[m] = (unsigned)f2bf(l0) | ((unsigned)f2bf(l1) << 16);
    }
    Hf[t] = make_uint4(hu[0], hu[1], hu[2], hu[3]);
    Lf[t] = make_uint4(lu[0], lu[1], lu[2], lu[3]);
  } else if (blk % 3 == 0) {   // edge role
    int e = (blk / 3) * 256 + threadIdx.x;
    if (e >= E) return;
    int s = src[e], d = dst[e];
    int bf = (unsigned)s >> 13;   // bucket of gathered row for fwd list (by dst)
    int bb = (unsigned)d >> 13;   // bucket of gathered row for bwd list (by src)
    unsigned rf = (unsigned)atomicAdd(&cin_p[(size_t)d * 16 + bf], 1);
    unsigned rb = (unsigned)atomicAdd(&cout_p[(size_t)s * 16 + bb], 1);
    rank_pk[e] = (rf & 0xFFFFu) | (rb << 16);
  } else {                     // conv role
    int cb = blk - blk / 3 - 1;
    int idx = cb * 256 + threadIdx.x;  // over n*32 float4s
    if (idx >= n * 32) return;
    float4 xv = ((const float4*)x)[idx];
    unsigned u0 = (unsigned)f2bf(xv.x) | ((unsigned)f2bf(xv.y) << 16);
    unsigned u1 = (unsigned)f2bf(xv.z) | ((unsigned)f2bf(xv.w) << 16);
    ((uint2*)xbu)[idx] = make_uint2(u0, u1);
  }
}

// Compact + scan-partials + rec deg/prefix fields.
// rec line (16 u32): [0]=offf [1]=degs [2..5]=basef p12,p34,p56,p7 [6,7]=pad
//                    [8]=offb [9]=degs [10..13]=baseb [14,15]=pad
__global__ __launch_bounds__(256) void k_compact_part(const int* __restrict__ cin_p,
                                                      const int* __restrict__ cout_p,
                                                      int* __restrict__ cin_d,
                                                      int* __restrict__ cout_d,
                                                      unsigned* __restrict__ rec,
                                                      int* __restrict__ partA,
                                                      int* __restrict__ partB, int n) {
  __shared__ int redA[256], redB[256];
  int t = threadIdx.x;
  int base = blockIdx.x * 2048 + t * 8;
  int sA = 0, sB = 0;
#pragma unroll
  for (int k = 0; k < 8; ++k) {
    int i = base + k;
    if (i < n) {
      unsigned cinv, coutv;
      unsigned f12, f34, f56, f7;
      {
        const int* pf = &cin_p[(size_t)i * 16];
        int c0 = pf[0], c1 = pf[1], c2 = pf[2], c3 = pf[3];
        int c4 = pf[4], c5 = pf[5], c6 = pf[6], c7 = pf[7];
        unsigned run = c0;
        unsigned p1 = run; run += c1; unsigned p2 = run; run += c2;
        unsigned p3 = run; run += c3; unsigned p4 = run; run += c4;
        unsigned p5 = run; run += c5; unsigned p6 = run; run += c6;
        unsigned p7 = run; run += c7;
        cin_d[i] = (int)run;
        sA += (int)run;
        cinv = (run > 65535u) ? 65535u : run;
        f12 = p1 | (p2 << 16); f34 = p3 | (p4 << 16);
        f56 = p5 | (p6 << 16); f7 = p7;
      }
      unsigned b12, b34, b56, b7;
      {
        const int* pf = &cout_p[(size_t)i * 16];
        int c0 = pf[0], c1 = pf[1], c2 = pf[2], c3 = pf[3];
        int c4 = pf[4], c5 = pf[5], c6 = pf[6], c7 = pf[7];
        unsigned run = c0;
        unsigned p1 = run; run += c1; unsigned p2 = run; run += c2;
        unsigned p3 = run; run += c3; unsigned p4 = run; run += c4;
        unsigned p5 = run; run += c5; unsigned p6 = run; run += c6;
        unsigned p7 = run; run += c7;
        cout_d[i] = (int)run;
        sB += (int)run;
        coutv = (run > 65535u) ? 65535u : run;
        b12 = p1 | (p2 << 16); b34 = p3 | (p4 << 16);
        b56 = p5 | (p6 << 16); b7 = p7;
      }
      unsigned degs = cinv | (coutv << 16);
      unsigned* r = &rec[(size_t)i * 16];
      r[1] = degs; r[2] = f12; r[3] = f34; r[4] = f56; r[5] = f7;
      r[9] = degs; r[10] = b12; r[11] = b34; r[12] = b56; r[13] = b7;
    }
  }
  redA[t] = sA; redB[t] = sB;
  __syncthreads();
  for (int o = 128; o > 0; o >>= 1) {
    if (t < o) { redA[t] += redA[t + o]; redB[t] += redB[t + o]; }
    __syncthreads();
  }
  if (t == 0) { partA[blockIdx.x] = redA[0]; partB[blockIdx.x] = redB[0]; }
}

__global__ __launch_bounds__(64) void k_scan_tops(int* __restrict__ partA,
                                                  int* __restrict__ partB, int nb) {
  int* part = blockIdx.y ? partB : partA;
  if (threadIdx.x == 0) {
    int run = 0;
    for (int i = 0; i < nb; ++i) { int v = part[i]; part[i] = run; run += v; }
  }
}

// Scan output: dense off arrays (for agg) + off fields in rec (for fill).
__global__ __launch_bounds__(256) void k_scan_out(const int* __restrict__ cntA,
                                                  const int* __restrict__ cntB,
                                                  const int* __restrict__ partA,
                                                  const int* __restrict__ partB,
                                                  int* __restrict__ offA,
                                                  int* __restrict__ offB,
                                                  unsigned* __restrict__ rec, int n) {
  const int* cnt = blockIdx.y ? cntB : cntA;
  const int* part = blockIdx.y ? partB : partA;
  int* off = blockIdx.y ? offB : offA;
  int fld = blockIdx.y ? 8 : 0;   // rec word for this direction's off
  __shared__ int ts[256];
  int t = threadIdx.x;
  int base = blockIdx.x * 2048 + t * 8;
  int v[8];
  int s = 0;
#pragma unroll
  for (int i = 0; i < 8; ++i) {
    int idx = base + i;
    int c = (idx < n) ? cnt[idx] : 0;
    v[i] = s;          // exclusive prefix within thread
    s += c;
  }
  ts[t] = s;
  __syncthreads();
  for (int o = 1; o < 256; o <<= 1) {
    int val = (t >= o) ? ts[t - o] : 0;
    __syncthreads();
    ts[t] += val;
    __syncthreads();
  }
  int blockbase = part[blockIdx.x] + (t ? ts[t - 1] : 0);
#pragma unroll
  for (int i = 0; i < 8; ++i) {
    int idx = base + i;
    if (idx <= n) {
      int val = blockbase + v[i];
      off[idx] = val;   // idx==n writes the total
      if (idx < n) rec[(size_t)idx * 16 + fld] = (unsigned)val;
    }
  }
}

// Atomic-free fill; 2 random 64B line touches per edge (rec[d], rec[s]).
__global__ __launch_bounds__(256) void k_fill(const int* __restrict__ src,
                                              const int* __restrict__ dst,
                                              const unsigned* __restrict__ rank_pk,
                                              const uint4* __restrict__ rec4,
                                              unsigned* __restrict__ epf,
                                              unsigned* __restrict__ epb, int E) {
  int e = blockIdx.x * 256 + threadIdx.x;
  if (e >= E) return;
  int s = src[e], d = dst[e];
  unsigned rp = rank_pk[e];
  int rf = (int)(rp & 0xFFFFu), rb = (int)(rp >> 16);
  int bf = (unsigned)s >> 13, bb = (unsigned)d >> 13;
  // F-half of d: slot0 = (offf, degs, p12, p34), slot1 = (p56, p7, -, -)
  uint4 f0 = rec4[(size_t)d * 4 + 0];
  uint4 f1 = rec4[(size_t)d * 4 + 1];
  // B-half of s: slot2 = (offb, degs, p12, p34), slot3 = (p56, p7, -, -)
  uint4 b0 = rec4[(size_t)s * 4 + 2];
  uint4 b1 = rec4[(size_t)s * 4 + 3];
  unsigned co = b0.y >> 16;       // cout of s (fwd weight deg)
  unsigned ci = f0.y & 0xFFFFu;   // cin of d (bwd weight deg)
  unsigned pf = pre8(f0.z, f0.w, f1.x, f1.y, bf);
  unsigned pb = pre8(b0.z, b0.w, b1.x, b1.y, bb);
  epf[f0.x + pf + (unsigned)rf] = ((unsigned)s << 16) | co;
  epb[b0.x + pb + (unsigned)rb] = ((unsigned)d << 16) | ci;
}

// Single-pass row-major aggregation (r11's flat kernel). 16 lanes/node,
// 4 nodes/wave, x4 unroll. Edge lists are bucket-major (sorted by gathered-id
// slab): all concurrent waves walk x-slabs 0..7 monotonically -> the active
// slab tends to stay L2-resident without any barriers or loop overhead.
__global__ __launch_bounds__(256) void k_agg6(const uint4* __restrict__ xb,
                                              const int* __restrict__ offA,
                                              const unsigned* __restrict__ epA,
                                              const int* __restrict__ offB,
                                              const unsigned* __restrict__ epB,
                                              uint4* __restrict__ outA,
                                              uint4* __restrict__ outB, int n) {
  int lane = threadIdx.x & 63;
  int gi = lane >> 4, c = lane & 15;     // node-in-wave, uint4 column
  int node = ((blockIdx.x * 256 + threadIdx.x) >> 6) * 4 + gi;
  if (node >= n) return;
  const int* off = blockIdx.y ? offB : offA;
  const unsigned* ep = blockIdx.y ? epB : epA;
  uint4* out = blockIdx.y ? outB : outA;

  int i = off[node], end = off[node + 1];
  float acc[8];
#pragma unroll
  for (int k = 0; k < 8; ++k) acc[k] = 0.f;

#define AGG_BODY(r_, w_)                                                      \
  acc[0] = fmaf(bflo(r_.x), w_, acc[0]); acc[1] = fmaf(bfhi(r_.x), w_, acc[1]); \
  acc[2] = fmaf(bflo(r_.y), w_, acc[2]); acc[3] = fmaf(bfhi(r_.y), w_, acc[3]); \
  acc[4] = fmaf(bflo(r_.z), w_, acc[4]); acc[5] = fmaf(bfhi(r_.z), w_, acc[5]); \
  acc[6] = fmaf(bflo(r_.w), w_, acc[6]); acc[7] = fmaf(bfhi(r_.w), w_, acc[7]);

  for (; i + 3 < end; i += 4) {
    unsigned e0 = ep[i], e1 = ep[i + 1], e2 = ep[i + 2], e3 = ep[i + 3];
    uint4 r0 = xb[(size_t)(e0 >> 16) * 16 + c];
    uint4 r1 = xb[(size_t)(e1 >> 16) * 16 + c];
    uint4 r2 = xb[(size_t)(e2 >> 16) * 16 + c];
    uint4 r3 = xb[(size_t)(e3 >> 16) * 16 + c];
    float w0 = 1.0f / (float)(e0 & 0xFFFFu);   // IEEE div: bit-exact vs table
    float w1 = 1.0f / (float)(e1 & 0xFFFFu);
    float w2 = 1.0f / (float)(e2 & 0xFFFFu);
    float w3 = 1.0f / (float)(e3 & 0xFFFFu);
    AGG_BODY(r0, w0)
    AGG_BODY(r1, w1)
    AGG_BODY(r2, w2)
    AGG_BODY(r3, w3)
  }
  for (; i < end; ++i) {
    unsigned e0 = ep[i];
    uint4 r0 = xb[(size_t)(e0 >> 16) * 16 + c];
    float w0 = 1.0f / (float)(e0 & 0xFFFFu);
    AGG_BODY(r0, w0)
  }
#undef AGG_BODY

  uint4 o;
  o.x = (unsigned)f2bf(acc[0]) | ((unsigned)f2bf(acc[1]) << 16);
  o.y = (unsigned)f2bf(acc[2]) | ((unsigned)f2bf(acc[3]) << 16);
  o.z = (unsigned)f2bf(acc[4]) | ((unsigned)f2bf(acc[5]) << 16);
  o.w = (unsigned)f2bf(acc[6]) | ((unsigned)f2bf(acc[7]) << 16);
  out[(size_t)node * 16 + c] = o;
}

// Barrier-free MFMA GEMM, fragment-major W (coalesced 1KB W-loads, L2-hit).
//  A-frag(mt): src4[(bm0+(2w+mt)*16+(lane&15))*16 + ko + (lane>>4)]
//  W-frag(nt): Wf[(kc*8+nt)*64 + lane]   (hi and lo arrays)
// If outb: write bf16(relu(h)) row-major (next layer's xbu). Else fp32 outf.
__global__ __launch_bounds__(256) void k_gemm(const unsigned* __restrict__ xbu,
                                              const unsigned* __restrict__ fwdb,
                                              const unsigned* __restrict__ bwdb,
                                              const uint4* __restrict__ Whf,
                                              const uint4* __restrict__ Wlf,
                                              const float* __restrict__ bias,
                                              unsigned short* __restrict__ outb,
                                              float* __restrict__ outf, int n) {
  int tid = threadIdx.x;
  int bm0 = blockIdx.x * 128;
  int w = tid >> 6, lane = tid & 63;
  int lr = lane & 15, q = lane >> 4;   // frag row-in-tile, k-quad

  f32x4 acc[2][8];
#pragma unroll
  for (int mt = 0; mt < 2; ++mt)
#pragma unroll
    for (int nt = 0; nt < 8; ++nt) acc[mt][nt] = (f32x4){0.f, 0.f, 0.f, 0.f};

  const uint4 zero4 = make_uint4(0u, 0u, 0u, 0u);

  int vr0 = bm0 + (2 * w + 0) * 16 + lr;
  int vr1 = bm0 + (2 * w + 1) * 16 + lr;
  bool ok0 = vr0 < n, ok1 = vr1 < n;

  for (int kc = 0; kc < 12; ++kc) {
    const uint4* src4 = (const uint4*)((kc < 4) ? xbu : ((kc < 8) ? fwdb : bwdb));
    int ko = (kc & 3) * 4;   // uint4 offset within row (16 uint4 = 128 bf16)
    uint4 a0u = ok0 ? src4[(size_t)vr0 * 16 + ko + q] : zero4;
    uint4 a1u = ok1 ? src4[(size_t)vr1 * 16 + ko + q] : zero4;
    bf16x8 a0 = as_bf16x8(a0u);
    bf16x8 a1 = as_bf16x8(a1u);
#pragma unroll
    for (int nt = 0; nt < 8; ++nt) {
      size_t wi = (size_t)((kc * 8 + nt) * 64 + lane);
      bf16x8 bh = as_bf16x8(Whf[wi]);
      bf16x8 bl = as_bf16x8(Wlf[wi]);
      acc[0][nt] = __builtin_amdgcn_mfma_f32_16x16x32_bf16(a0, bh, acc[0][nt], 0, 0, 0);
      acc[0][nt] = __builtin_amdgcn_mfma_f32_16x16x32_bf16(a0, bl, acc[0][nt], 0, 0, 0);
      acc[1][nt] = __builtin_amdgcn_mfma_f32_16x16x32_bf16(a1, bh, acc[1][nt], 0, 0, 0);
      acc[1][nt] = __builtin_amdgcn_mfma_f32_16x16x32_bf16(a1, bl, acc[1][nt], 0, 0, 0);
    }
  }

  // Epilogue. C layout: col = lane&15, row = (lane>>4)*4 + reg  (m89-verified)
  int col = lane & 15;
  float bv[8];
#pragma unroll
  for (int nt = 0; nt < 8; ++nt) bv[nt] = bias[nt * 16 + col];
#pragma unroll
  for (int mt = 0; mt < 2; ++mt) {
    int rowbase = bm0 + w * 32 + mt * 16 + (lane >> 4) * 4;
#pragma unroll
    for (int reg = 0; reg < 4; ++reg) {
      int row = rowbase + reg;
      if (row >= n) continue;
      if (outb) {
#pragma unroll
        for (int nt = 0; nt < 8; ++nt) {
          float t = fmaxf(acc[mt][nt][reg] + bv[nt], 0.f);   // relu layers
          outb[(size_t)row * 128 + nt * 16 + col] = f2bf(t);
        }
      } else {
#pragma unroll
        for (int nt = 0; nt < 8; ++nt) {
          float t = acc[mt][nt][reg] + bv[nt];
          outf[(size_t)row * 128 + nt * 16 + col] = t;
        }
      }
    }
  }
}

extern "C" void kernel_launch(void* const* d_in, const int* in_sizes, int n_in,
                              void* d_out, int out_size, void* d_ws, size_t ws_size,
                              hipStream_t stream) {
  const int D = 128;
  const int N = in_sizes[0] / D;
  const int E = in_sizes[7];

  const float* x  = (const float*)d_in[0];
  const float* W0 = (const float*)d_in[1];
  const float* b0 = (const float*)d_in[2];
  const float* W1 = (const float*)d_in[3];
  const float* b1 = (const float*)d_in[4];
  const float* W2 = (const float*)d_in[5];
  const float* b2 = (const float*)d_in[6];
  const int* src  = (const int*)d_in[7];
  const int* dst  = (const int*)d_in[8];
  float* out = (float*)d_out;

  char* p = (char*)d_ws;
  auto alloc = [&](size_t bytes) -> char* {
    char* r = p;
    p += (bytes + 15) & ~(size_t)15;
    return r;
  };
  int* cin_p  = (int*)alloc((size_t)N * 64);   // padded: 8 bucket slots / 64B line
  int* cout_p = (int*)alloc((size_t)N * 64);
  int* cin_d  = (int*)alloc((size_t)N * 4);    // dense totals for scan
  int* cout_d = (int*)alloc((size_t)N * 4);
  int* offf = (int*)alloc((size_t)(N + 1) * 4);
  int* offb = (int*)alloc((size_t)(N + 1) * 4);
  unsigned* rec = (unsigned*)alloc((size_t)N * 64);  // 64B fill record / node
  unsigned* rank_pk = (unsigned*)alloc((size_t)E * 4);   // rankf | rankb<<16
  unsigned* epf = (unsigned*)alloc((size_t)E * 4);       // (u<<16 | deg) payload
  unsigned* epb = (unsigned*)alloc((size_t)E * 4);
  unsigned* xbu = (unsigned*)alloc((size_t)N * 64 * 4);  // row-major bf16x2
  unsigned* fwdb = (unsigned*)alloc((size_t)N * 64 * 4);
  unsigned* bwdb = (unsigned*)alloc((size_t)N * 64 * 4);
  uint4* Whf[3], *Wlf[3];                     // fragment-major split-bf16 W
  for (int l = 0; l < 3; ++l) {
    Whf[l] = (uint4*)alloc((size_t)12 * 8 * 64 * 16);
    Wlf[l] = (uint4*)alloc((size_t)12 * 8 * 64 * 16);
  }
  int nbScan = (N + 1 + 2047) / 2048;
  int* partA = (int*)alloc((size_t)(nbScan + 1) * 4);
  int* partB = (int*)alloc((size_t)(nbScan + 1) * 4);

  hipMemsetAsync(cin_p, 0, (size_t)2 * N * 64, stream);  // cin_p+cout_p contiguous

  int edgeBlocks = (E + 255) / 256;
  int convBlocks = (N * 32 + 255) / 256;
  int wBase = edgeBlocks + convBlocks + 2;   // edge+conv interleave region
  int fusedBlocks = wBase + 72;              // + 3x24 frag-major wconv blocks
  k_front<<<fusedBlocks, 256, 0, stream>>>(src, dst, cin_p, cout_p, rank_pk,
                                           E, wBase, x, xbu, N,
                                           W0, W1, W2,
                                           Whf[0], Whf[1], Whf[2],
                                           Wlf[0], Wlf[1], Wlf[2]);
  k_compact_part<<<nbScan, 256, 0, stream>>>(cin_p, cout_p, cin_d, cout_d,
                                             rec, partA, partB, N);
  k_scan_tops<<<dim3(1, 2), 64, 0, stream>>>(partA, partB, nbScan);
  k_scan_out<<<dim3(nbScan, 2), 256, 0, stream>>>(cin_d, cout_d, partA, partB,
                                                  offf, offb, rec, N);
  k_fill<<<(E + 255) / 256, 256, 0, stream>>>(src, dst, rank_pk,
                                              (const uint4*)rec, epf, epb, E);

  const float* bs[3] = {b0, b1, b2};
  int aggBlocks = (N + 15) / 16;          // 16 nodes/block (4 waves); dir = y
  int gemmBlocks = (N + 127) / 128;

  for (int l = 0; l < 3; ++l) {
    k_agg6<<<dim3(aggBlocks, 2), 256, 0, stream>>>(
        (const uint4*)xbu, offf, epf, offb, epb,
        (uint4*)fwdb, (uint4*)bwdb, N);
    if (l < 2) {
      k_gemm<<<gemmBlocks, 256, 0, stream>>>(xbu, fwdb, bwdb, Whf[l], Wlf[l],
                                             bs[l], (unsigned short*)xbu, nullptr, N);
    } else {
      k_gemm<<<gemmBlocks, 256, 0, stream>>>(xbu, fwdb, bwdb, Whf[l], Wlf[l],
                                             bs[l], nullptr, out, N);
    }
  }
}

// Round 11
// 441.138 us; speedup vs baseline: 1.3629x; 1.1604x over previous
//
#include <hip/hip_runtime.h>
#include <cstdint>

// ---------------------------------------------------------------------------
// DirGraphSAGE round 19: agg+gemm FUSION (both directions in one block).
//  Structure: block = 16 nodes, 512 threads (8 waves). Waves 0-3 aggregate
//  fwd, waves 4-7 bwd (same flat x4 bucket-sorted gather as r14). Results
//  drop into a 12.5KB LDS tile next to the staged xbu rows ->  one barrier ->
//  each wave computes one 16x16 output tile (nt = wave id) with 24 chained
//  MFMAs; W read fragment-major (r18 layout, L2-resident, coalesced 1KB).
//  Eliminates: 3 gemm dispatches, the fwdb/bwdb global round-trip (agg
//  WRITE 25->13MB), gemm's A re-read. xbu double-buffered across layers
//  (fused kernel writes next xbu while others still gather current).
//  Bit-exact: agg loop unchanged; LDS A bytes = old fwdb/bwdb/xbu bytes;
//  MFMA order per output element unchanged (kc 0..11, hi then lo).
//  A-row LDS stride 49 uint4 (784B): bank stride 196%32=4 -> 2-way (free).
// ---------------------------------------------------------------------------

typedef __bf16 bf16x8 __attribute__((ext_vector_type(8)));
typedef float f32x4 __attribute__((ext_vector_type(4)));

__device__ __forceinline__ unsigned short f2bf(float f) {
  unsigned u = __float_as_uint(f);
  u += 0x7FFFu + ((u >> 16) & 1u);   // round-to-nearest-even
  return (unsigned short)(u >> 16);
}
__device__ __forceinline__ float bflo(unsigned u) { return __uint_as_float(u << 16); }
__device__ __forceinline__ float bfhi(unsigned u) { return __uint_as_float(u & 0xFFFF0000u); }

__device__ __forceinline__ bf16x8 as_bf16x8(uint4 u) {
  union { uint4 u4; bf16x8 b8; } cv; cv.u4 = u; return cv.b8;
}

// prefix for bucket b (0..7) from packed words p12,p34,p56,p7; p0 = 0.
__device__ __forceinline__ unsigned pre8(unsigned a, unsigned b, unsigned c,
                                         unsigned d, int bk) {
  if (bk == 0) return 0u;
  int k = bk - 1;  // 0..6
  unsigned w = (k < 2) ? a : (k < 4) ? b : (k < 6) ? c : d;
  return (k & 1) ? (w >> 16) : (w & 0xFFFFu);
}

// Fused front kernel, 3 roles by blockIdx (r18 version):
//  role E (blk%3==0, blk<3*edgeBlocks): per-(node,bucket) rank atomics
//  role C (other blk < wBase): x -> bf16 row-major xbu
//  role W (blk >= wBase): W -> fragment-major split-bf16 Wfrag[kc][nt][lane]
__global__ __launch_bounds__(256) void k_front(const int* __restrict__ src,
                                               const int* __restrict__ dst,
                                               int* __restrict__ cin_p,
                                               int* __restrict__ cout_p,
                                               unsigned* __restrict__ rank_pk,
                                               int E, int wBase,
                                               const float* __restrict__ x,
                                               unsigned* __restrict__ xbu, int n,
                                               const float* __restrict__ Wa,
                                               const float* __restrict__ Wb,
                                               const float* __restrict__ Wc,
                                               uint4* __restrict__ Ha,
                                               uint4* __restrict__ Hb,
                                               uint4* __restrict__ Hc,
                                               uint4* __restrict__ La,
                                               uint4* __restrict__ Lb,
                                               uint4* __restrict__ Lc) {
  int blk = blockIdx.x;
  if (blk >= wBase) {          // W-conv role: 72 blocks (3 x 24)
    int wblk = blk - wBase;
    int y = wblk / 24;
    int t = (wblk - y * 24) * 256 + threadIdx.x;   // 0..6143 per matrix
    if (t >= 12 * 8 * 64) return;
    const float* W = (y == 0) ? Wa : ((y == 1) ? Wb : Wc);
    uint4* Hf = (y == 0) ? Ha : ((y == 1) ? Hb : Hc);
    uint4* Lf = (y == 0) ? La : ((y == 1) ? Lb : Lc);
    int kc = t >> 9;            // /512
    int rem = t & 511;
    int nt = rem >> 6;
    int lane = rem & 63;
    int q = lane >> 4, lr = lane & 15;
    int j = nt * 16 + lr;
    int ks = (kc * 4 + q) * 8;
    unsigned hu[4], lu[4];
#pragma unroll
    for (int m = 0; m < 4; ++m) {
      float w0 = W[(size_t)(ks + 2 * m) * 128 + j];
      float w1 = W[(size_t)(ks + 2 * m + 1) * 128 + j];
      unsigned short h0 = f2bf(w0), h1 = f2bf(w1);
      float l0 = w0 - __uint_as_float((unsigned)h0 << 16);
      float l1 = w1 - __uint_as_float((unsigned)h1 << 16);
      hu[m] = (unsigned)h0 | ((unsigned)h1 << 16);
      lu[m] = (unsigned)f2bf(l0) | ((unsigned)f2bf(l1) << 16);
    }
    Hf[t] = make_uint4(hu[0], hu[1], hu[2], hu[3]);
    Lf[t] = make_uint4(lu[0], lu[1], lu[2], lu[3]);
  } else if (blk % 3 == 0) {   // edge role
    int e = (blk / 3) * 256 + threadIdx.x;
    if (e >= E) return;
    int s = src[e], d = dst[e];
    int bf = (unsigned)s >> 13;   // bucket of gathered row for fwd list (by dst)
    int bb = (unsigned)d >> 13;   // bucket of gathered row for bwd list (by src)
    unsigned rf = (unsigned)atomicAdd(&cin_p[(size_t)d * 16 + bf], 1);
    unsigned rb = (unsigned)atomicAdd(&cout_p[(size_t)s * 16 + bb], 1);
    rank_pk[e] = (rf & 0xFFFFu) | (rb << 16);
  } else {                     // conv role
    int cb = blk - blk / 3 - 1;
    int idx = cb * 256 + threadIdx.x;  // over n*32 float4s
    if (idx >= n * 32) return;
    float4 xv = ((const float4*)x)[idx];
    unsigned u0 = (unsigned)f2bf(xv.x) | ((unsigned)f2bf(xv.y) << 16);
    unsigned u1 = (unsigned)f2bf(xv.z) | ((unsigned)f2bf(xv.w) << 16);
    ((uint2*)xbu)[idx] = make_uint2(u0, u1);
  }
}

// Compact + scan-partials + rec deg/prefix fields.
// rec line (16 u32): [0]=offf [1]=degs [2..5]=basef p12,p34,p56,p7 [6,7]=pad
//                    [8]=offb [9]=degs [10..13]=baseb [14,15]=pad
__global__ __launch_bounds__(256) void k_compact_part(const int* __restrict__ cin_p,
                                                      const int* __restrict__ cout_p,
                                                      int* __restrict__ cin_d,
                                                      int* __restrict__ cout_d,
                                                      unsigned* __restrict__ rec,
                                                      int* __restrict__ partA,
                                                      int* __restrict__ partB, int n) {
  __shared__ int redA[256], redB[256];
  int t = threadIdx.x;
  int base = blockIdx.x * 2048 + t * 8;
  int sA = 0, sB = 0;
#pragma unroll
  for (int k = 0; k < 8; ++k) {
    int i = base + k;
    if (i < n) {
      unsigned cinv, coutv;
      unsigned f12, f34, f56, f7;
      {
        const int* pf = &cin_p[(size_t)i * 16];
        int c0 = pf[0], c1 = pf[1], c2 = pf[2], c3 = pf[3];
        int c4 = pf[4], c5 = pf[5], c6 = pf[6], c7 = pf[7];
        unsigned run = c0;
        unsigned p1 = run; run += c1; unsigned p2 = run; run += c2;
        unsigned p3 = run; run += c3; unsigned p4 = run; run += c4;
        unsigned p5 = run; run += c5; unsigned p6 = run; run += c6;
        unsigned p7 = run; run += c7;
        cin_d[i] = (int)run;
        sA += (int)run;
        cinv = (run > 65535u) ? 65535u : run;
        f12 = p1 | (p2 << 16); f34 = p3 | (p4 << 16);
        f56 = p5 | (p6 << 16); f7 = p7;
      }
      unsigned b12, b34, b56, b7;
      {
        const int* pf = &cout_p[(size_t)i * 16];
        int c0 = pf[0], c1 = pf[1], c2 = pf[2], c3 = pf[3];
        int c4 = pf[4], c5 = pf[5], c6 = pf[6], c7 = pf[7];
        unsigned run = c0;
        unsigned p1 = run; run += c1; unsigned p2 = run; run += c2;
        unsigned p3 = run; run += c3; unsigned p4 = run; run += c4;
        unsigned p5 = run; run += c5; unsigned p6 = run; run += c6;
        unsigned p7 = run; run += c7;
        cout_d[i] = (int)run;
        sB += (int)run;
        coutv = (run > 65535u) ? 65535u : run;
        b12 = p1 | (p2 << 16); b34 = p3 | (p4 << 16);
        b56 = p5 | (p6 << 16); b7 = p7;
      }
      unsigned degs = cinv | (coutv << 16);
      unsigned* r = &rec[(size_t)i * 16];
      r[1] = degs; r[2] = f12; r[3] = f34; r[4] = f56; r[5] = f7;
      r[9] = degs; r[10] = b12; r[11] = b34; r[12] = b56; r[13] = b7;
    }
  }
  redA[t] = sA; redB[t] = sB;
  __syncthreads();
  for (int o = 128; o > 0; o >>= 1) {
    if (t < o) { redA[t] += redA[t + o]; redB[t] += redB[t + o]; }
    __syncthreads();
  }
  if (t == 0) { partA[blockIdx.x] = redA[0]; partB[blockIdx.x] = redB[0]; }
}

__global__ __launch_bounds__(64) void k_scan_tops(int* __restrict__ partA,
                                                  int* __restrict__ partB, int nb) {
  int* part = blockIdx.y ? partB : partA;
  if (threadIdx.x == 0) {
    int run = 0;
    for (int i = 0; i < nb; ++i) { int v = part[i]; part[i] = run; run += v; }
  }
}

// Scan output: dense off arrays (for agg) + off fields in rec (for fill).
__global__ __launch_bounds__(256) void k_scan_out(const int* __restrict__ cntA,
                                                  const int* __restrict__ cntB,
                                                  const int* __restrict__ partA,
                                                  const int* __restrict__ partB,
                                                  int* __restrict__ offA,
                                                  int* __restrict__ offB,
                                                  unsigned* __restrict__ rec, int n) {
  const int* cnt = blockIdx.y ? cntB : cntA;
  const int* part = blockIdx.y ? partB : partA;
  int* off = blockIdx.y ? offB : offA;
  int fld = blockIdx.y ? 8 : 0;   // rec word for this direction's off
  __shared__ int ts[256];
  int t = threadIdx.x;
  int base = blockIdx.x * 2048 + t * 8;
  int v[8];
  int s = 0;
#pragma unroll
  for (int i = 0; i < 8; ++i) {
    int idx = base + i;
    int c = (idx < n) ? cnt[idx] : 0;
    v[i] = s;          // exclusive prefix within thread
    s += c;
  }
  ts[t] = s;
  __syncthreads();
  for (int o = 1; o < 256; o <<= 1) {
    int val = (t >= o) ? ts[t - o] : 0;
    __syncthreads();
    ts[t] += val;
    __syncthreads();
  }
  int blockbase = part[blockIdx.x] + (t ? ts[t - 1] : 0);
#pragma unroll
  for (int i = 0; i < 8; ++i) {
    int idx = base + i;
    if (idx <= n) {
      int val = blockbase + v[i];
      off[idx] = val;   // idx==n writes the total
      if (idx < n) rec[(size_t)idx * 16 + fld] = (unsigned)val;
    }
  }
}

// Atomic-free fill; 2 random 64B line touches per edge (rec[d], rec[s]).
__global__ __launch_bounds__(256) void k_fill(const int* __restrict__ src,
                                              const int* __restrict__ dst,
                                              const unsigned* __restrict__ rank_pk,
                                              const uint4* __restrict__ rec4,
                                              unsigned* __restrict__ epf,
                                              unsigned* __restrict__ epb, int E) {
  int e = blockIdx.x * 256 + threadIdx.x;
  if (e >= E) return;
  int s = src[e], d = dst[e];
  unsigned rp = rank_pk[e];
  int rf = (int)(rp & 0xFFFFu), rb = (int)(rp >> 16);
  int bf = (unsigned)s >> 13, bb = (unsigned)d >> 13;
  uint4 f0 = rec4[(size_t)d * 4 + 0];
  uint4 f1 = rec4[(size_t)d * 4 + 1];
  uint4 b0 = rec4[(size_t)s * 4 + 2];
  uint4 b1 = rec4[(size_t)s * 4 + 3];
  unsigned co = b0.y >> 16;       // cout of s (fwd weight deg)
  unsigned ci = f0.y & 0xFFFFu;   // cin of d (bwd weight deg)
  unsigned pf = pre8(f0.z, f0.w, f1.x, f1.y, bf);
  unsigned pb = pre8(b0.z, b0.w, b1.x, b1.y, bb);
  epf[f0.x + pf + (unsigned)rf] = ((unsigned)s << 16) | co;
  epb[b0.x + pb + (unsigned)rb] = ((unsigned)d << 16) | ci;
}

// Fused aggregation + GEMM. Block = 16 nodes, 512 threads (8 waves).
// Waves 0-3: fwd agg (4 nodes each); waves 4-7: bwd agg. LDS A-tile
// [16 rows][49 uint4]: cols 0-15 xbu, 16-31 fwd, 32-47 bwd, 48 pad.
// After barrier: wave w computes output n-tile nt=w (16x16) via 12kc x
// (hi,lo) MFMA, A from LDS, W frag-major from global (L2-resident).
__global__ __launch_bounds__(512) void k_fused(const uint4* __restrict__ xb,
                                               const int* __restrict__ offA,
                                               const unsigned* __restrict__ epA,
                                               const int* __restrict__ offB,
                                               const unsigned* __restrict__ epB,
                                               const uint4* __restrict__ Whf,
                                               const uint4* __restrict__ Wlf,
                                               const float* __restrict__ bias,
                                               unsigned short* __restrict__ outb,
                                               float* __restrict__ outf, int n) {
  __shared__ uint4 sA[16 * 49];   // 12544 B
  int tid = threadIdx.x;
  int w = tid >> 6, lane = tid & 63;
  int gi = lane >> 4, c = lane & 15;
  int blk = blockIdx.x;
  int local = (w & 3) * 4 + gi;   // node-in-block 0..15
  int node = blk * 16 + local;
  bool isFwd = w < 4;

  // stage this block's 16 xbu rows (A cols 0..15)
  if (tid < 256) {
    int r = tid >> 4, col = tid & 15;
    int v = blk * 16 + r;
    sA[r * 49 + col] = (v < n) ? xb[(size_t)v * 16 + col]
                               : make_uint4(0u, 0u, 0u, 0u);
  }

  // aggregation (flat x4, bucket-sorted ep): each wave 4 nodes, 1 direction
  const int* off = isFwd ? offA : offB;
  const unsigned* ep = isFwd ? epA : epB;
  int i = 0, end = 0;
  if (node < n) { i = off[node]; end = off[node + 1]; }
  float acc[8];
#pragma unroll
  for (int k = 0; k < 8; ++k) acc[k] = 0.f;

#define AGG_BODY(r_, w_)                                                      \
  acc[0] = fmaf(bflo(r_.x), w_, acc[0]); acc[1] = fmaf(bfhi(r_.x), w_, acc[1]); \
  acc[2] = fmaf(bflo(r_.y), w_, acc[2]); acc[3] = fmaf(bfhi(r_.y), w_, acc[3]); \
  acc[4] = fmaf(bflo(r_.z), w_, acc[4]); acc[5] = fmaf(bfhi(r_.z), w_, acc[5]); \
  acc[6] = fmaf(bflo(r_.w), w_, acc[6]); acc[7] = fmaf(bfhi(r_.w), w_, acc[7]);

  for (; i + 3 < end; i += 4) {
    unsigned e0 = ep[i], e1 = ep[i + 1], e2 = ep[i + 2], e3 = ep[i + 3];
    uint4 r0 = xb[(size_t)(e0 >> 16) * 16 + c];
    uint4 r1 = xb[(size_t)(e1 >> 16) * 16 + c];
    uint4 r2 = xb[(size_t)(e2 >> 16) * 16 + c];
    uint4 r3 = xb[(size_t)(e3 >> 16) * 16 + c];
    float w0 = 1.0f / (float)(e0 & 0xFFFFu);   // IEEE div: bit-exact
    float w1 = 1.0f / (float)(e1 & 0xFFFFu);
    float w2 = 1.0f / (float)(e2 & 0xFFFFu);
    float w3 = 1.0f / (float)(e3 & 0xFFFFu);
    AGG_BODY(r0, w0)
    AGG_BODY(r1, w1)
    AGG_BODY(r2, w2)
    AGG_BODY(r3, w3)
  }
  for (; i < end; ++i) {
    unsigned e0 = ep[i];
    uint4 r0 = xb[(size_t)(e0 >> 16) * 16 + c];
    float w0 = 1.0f / (float)(e0 & 0xFFFFu);
    AGG_BODY(r0, w0)
  }
#undef AGG_BODY

  uint4 o;
  o.x = (unsigned)f2bf(acc[0]) | ((unsigned)f2bf(acc[1]) << 16);
  o.y = (unsigned)f2bf(acc[2]) | ((unsigned)f2bf(acc[3]) << 16);
  o.z = (unsigned)f2bf(acc[4]) | ((unsigned)f2bf(acc[5]) << 16);
  o.w = (unsigned)f2bf(acc[6]) | ((unsigned)f2bf(acc[7]) << 16);
  sA[local * 49 + (isFwd ? 16 : 32) + c] = o;   // A cols 16-31 fwd / 32-47 bwd
  __syncthreads();

  // GEMM phase: wave w -> output n-tile nt = w
  int nt = w;
  int lr = lane & 15, q = lane >> 4;
  f32x4 cc = (f32x4){0.f, 0.f, 0.f, 0.f};
  for (int kc = 0; kc < 12; ++kc) {
    bf16x8 a = as_bf16x8(sA[lr * 49 + kc * 4 + q]);
    size_t wi = (size_t)((kc * 8 + nt) * 64 + lane);
    bf16x8 bh = as_bf16x8(Whf[wi]);
    bf16x8 bl = as_bf16x8(Wlf[wi]);
    cc = __builtin_amdgcn_mfma_f32_16x16x32_bf16(a, bh, cc, 0, 0, 0);
    cc = __builtin_amdgcn_mfma_f32_16x16x32_bf16(a, bl, cc, 0, 0, 0);
  }

  // Epilogue. C layout: col = lane&15, row = (lane>>4)*4 + reg (m89-verified)
  float bv = bias[nt * 16 + lr];
  int colg = nt * 16 + lr;
#pragma unroll
  for (int reg = 0; reg < 4; ++reg) {
    int row = blk * 16 + q * 4 + reg;
    if (row >= n) continue;
    if (outb) {
      float t = fmaxf(cc[reg] + bv, 0.f);
      outb[(size_t)row * 128 + colg] = f2bf(t);
    } else {
      outf[(size_t)row * 128 + colg] = cc[reg] + bv;
    }
  }
}

extern "C" void kernel_launch(void* const* d_in, const int* in_sizes, int n_in,
                              void* d_out, int out_size, void* d_ws, size_t ws_size,
                              hipStream_t stream) {
  const int D = 128;
  const int N = in_sizes[0] / D;
  const int E = in_sizes[7];

  const float* x  = (const float*)d_in[0];
  const float* W0 = (const float*)d_in[1];
  const float* b0 = (const float*)d_in[2];
  const float* W1 = (const float*)d_in[3];
  const float* b1 = (const float*)d_in[4];
  const float* W2 = (const float*)d_in[5];
  const float* b2 = (const float*)d_in[6];
  const int* src  = (const int*)d_in[7];
  const int* dst  = (const int*)d_in[8];
  float* out = (float*)d_out;

  char* p = (char*)d_ws;
  auto alloc = [&](size_t bytes) -> char* {
    char* r = p;
    p += (bytes + 15) & ~(size_t)15;
    return r;
  };
  int* cin_p  = (int*)alloc((size_t)N * 64);   // padded: 8 bucket slots / 64B line
  int* cout_p = (int*)alloc((size_t)N * 64);
  int* cin_d  = (int*)alloc((size_t)N * 4);    // dense totals for scan
  int* cout_d = (int*)alloc((size_t)N * 4);
  int* offf = (int*)alloc((size_t)(N + 1) * 4);
  int* offb = (int*)alloc((size_t)(N + 1) * 4);
  unsigned* rec = (unsigned*)alloc((size_t)N * 64);  // 64B fill record / node
  unsigned* rank_pk = (unsigned*)alloc((size_t)E * 4);   // rankf | rankb<<16
  unsigned* epf = (unsigned*)alloc((size_t)E * 4);       // (u<<16 | deg) payload
  unsigned* epb = (unsigned*)alloc((size_t)E * 4);
  unsigned* xbuA = (unsigned*)alloc((size_t)N * 64 * 4); // double-buffered bf16 x
  unsigned* xbuB = (unsigned*)alloc((size_t)N * 64 * 4);
  uint4* Whf[3], *Wlf[3];                     // fragment-major split-bf16 W
  for (int l = 0; l < 3; ++l) {
    Whf[l] = (uint4*)alloc((size_t)12 * 8 * 64 * 16);
    Wlf[l] = (uint4*)alloc((size_t)12 * 8 * 64 * 16);
  }
  int nbScan = (N + 1 + 2047) / 2048;
  int* partA = (int*)alloc((size_t)(nbScan + 1) * 4);
  int* partB = (int*)alloc((size_t)(nbScan + 1) * 4);

  hipMemsetAsync(cin_p, 0, (size_t)2 * N * 64, stream);  // cin_p+cout_p contiguous

  int edgeBlocks = (E + 255) / 256;
  int convBlocks = (N * 32 + 255) / 256;
  int wBase = edgeBlocks + convBlocks + 2;   // edge+conv interleave region
  int fusedBlocks = wBase + 72;              // + 3x24 frag-major wconv blocks
  k_front<<<fusedBlocks, 256, 0, stream>>>(src, dst, cin_p, cout_p, rank_pk,
                                           E, wBase, x, xbuA, N,
                                           W0, W1, W2,
                                           Whf[0], Whf[1], Whf[2],
                                           Wlf[0], Wlf[1], Wlf[2]);
  k_compact_part<<<nbScan, 256, 0, stream>>>(cin_p, cout_p, cin_d, cout_d,
                                             rec, partA, partB, N);
  k_scan_tops<<<dim3(1, 2), 64, 0, stream>>>(partA, partB, nbScan);
  k_scan_out<<<dim3(nbScan, 2), 256, 0, stream>>>(cin_d, cout_d, partA, partB,
                                                  offf, offb, rec, N);
  k_fill<<<(E + 255) / 256, 256, 0, stream>>>(src, dst, rank_pk,
                                              (const uint4*)rec, epf, epb, E);

  const float* bs[3] = {b0, b1, b2};
  int fuseBlocks = (N + 15) / 16;   // 16 nodes/block, 512 threads

  // layer 0: xbuA -> xbuB ; layer 1: xbuB -> xbuA ; layer 2: xbuA -> out(fp32)
  k_fused<<<fuseBlocks, 512, 0, stream>>>(
      (const uint4*)xbuA, offf, epf, offb, epb, Whf[0], Wlf[0], bs[0],
      (unsigned short*)xbuB, nullptr, N);
  k_fused<<<fuseBlocks, 512, 0, stream>>>(
      (const uint4*)xbuB, offf, epf, offb, epb, Whf[1], Wlf[1], bs[1],
      (unsigned short*)xbuA, nullptr, N);
  k_fused<<<fuseBlocks, 512, 0, stream>>>(
      (const uint4*)xbuA, offf, epf, offb, epb, Whf[2], Wlf[2], bs[2],
      nullptr, out, N);
}

// Round 12
// 430.263 us; speedup vs baseline: 1.3973x; 1.0253x over previous
//
#include <hip/hip_runtime.h>
#include <cstdint>

// ---------------------------------------------------------------------------
// DirGraphSAGE round 20: 32-node fused blocks + W register reuse.
//  r19 post-mortem: fusion won (441us) but the GEMM phase re-fetches 24KB of
//  frag-major W per wave per block = 600MB L2 traffic/dispatch (~17us) - the
//  marginal cost over pure agg. Fix: 32 nodes/block (512 thr): each 16-lane
//  slot aggregates 2 nodes sequentially (same total edge work, better degree
//  averaging at the barrier); GEMM loads W once per kc into regs and reuses
//  across both M-tiles -> W L2 traffic halved (300MB), W-load instrs halved.
//  LDS 32x49 uint4 = 25KB (still 4 blocks/CU, thread-bound). Per-element
//  MFMA order unchanged (kc 0..11, hi,lo) -> absmax bit-identical.
//  Everything else byte-identical to r19.
// ---------------------------------------------------------------------------

typedef __bf16 bf16x8 __attribute__((ext_vector_type(8)));
typedef float f32x4 __attribute__((ext_vector_type(4)));

__device__ __forceinline__ unsigned short f2bf(float f) {
  unsigned u = __float_as_uint(f);
  u += 0x7FFFu + ((u >> 16) & 1u);   // round-to-nearest-even
  return (unsigned short)(u >> 16);
}
__device__ __forceinline__ float bflo(unsigned u) { return __uint_as_float(u << 16); }
__device__ __forceinline__ float bfhi(unsigned u) { return __uint_as_float(u & 0xFFFF0000u); }

__device__ __forceinline__ bf16x8 as_bf16x8(uint4 u) {
  union { uint4 u4; bf16x8 b8; } cv; cv.u4 = u; return cv.b8;
}

// prefix for bucket b (0..7) from packed words p12,p34,p56,p7; p0 = 0.
__device__ __forceinline__ unsigned pre8(unsigned a, unsigned b, unsigned c,
                                         unsigned d, int bk) {
  if (bk == 0) return 0u;
  int k = bk - 1;  // 0..6
  unsigned w = (k < 2) ? a : (k < 4) ? b : (k < 6) ? c : d;
  return (k & 1) ? (w >> 16) : (w & 0xFFFFu);
}

// Fused front kernel, 3 roles by blockIdx (r18 version):
//  role E (blk%3==0, blk<3*edgeBlocks): per-(node,bucket) rank atomics
//  role C (other blk < wBase): x -> bf16 row-major xbu
//  role W (blk >= wBase): W -> fragment-major split-bf16 Wfrag[kc][nt][lane]
__global__ __launch_bounds__(256) void k_front(const int* __restrict__ src,
                                               const int* __restrict__ dst,
                                               int* __restrict__ cin_p,
                                               int* __restrict__ cout_p,
                                               unsigned* __restrict__ rank_pk,
                                               int E, int wBase,
                                               const float* __restrict__ x,
                                               unsigned* __restrict__ xbu, int n,
                                               const float* __restrict__ Wa,
                                               const float* __restrict__ Wb,
                                               const float* __restrict__ Wc,
                                               uint4* __restrict__ Ha,
                                               uint4* __restrict__ Hb,
                                               uint4* __restrict__ Hc,
                                               uint4* __restrict__ La,
                                               uint4* __restrict__ Lb,
                                               uint4* __restrict__ Lc) {
  int blk = blockIdx.x;
  if (blk >= wBase) {          // W-conv role: 72 blocks (3 x 24)
    int wblk = blk - wBase;
    int y = wblk / 24;
    int t = (wblk - y * 24) * 256 + threadIdx.x;   // 0..6143 per matrix
    if (t >= 12 * 8 * 64) return;
    const float* W = (y == 0) ? Wa : ((y == 1) ? Wb : Wc);
    uint4* Hf = (y == 0) ? Ha : ((y == 1) ? Hb : Hc);
    uint4* Lf = (y == 0) ? La : ((y == 1) ? Lb : Lc);
    int kc = t >> 9;            // /512
    int rem = t & 511;
    int nt = rem >> 6;
    int lane = rem & 63;
    int q = lane >> 4, lr = lane & 15;
    int j = nt * 16 + lr;
    int ks = (kc * 4 + q) * 8;
    unsigned hu[4], lu[4];
#pragma unroll
    for (int m = 0; m < 4; ++m) {
      float w0 = W[(size_t)(ks + 2 * m) * 128 + j];
      float w1 = W[(size_t)(ks + 2 * m + 1) * 128 + j];
      unsigned short h0 = f2bf(w0), h1 = f2bf(w1);
      float l0 = w0 - __uint_as_float((unsigned)h0 << 16);
      float l1 = w1 - __uint_as_float((unsigned)h1 << 16);
      hu[m] = (unsigned)h0 | ((unsigned)h1 << 16);
      lu[m] = (unsigned)f2bf(l0) | ((unsigned)f2bf(l1) << 16);
    }
    Hf[t] = make_uint4(hu[0], hu[1], hu[2], hu[3]);
    Lf[t] = make_uint4(lu[0], lu[1], lu[2], lu[3]);
  } else if (blk % 3 == 0) {   // edge role
    int e = (blk / 3) * 256 + threadIdx.x;
    if (e >= E) return;
    int s = src[e], d = dst[e];
    int bf = (unsigned)s >> 13;   // bucket of gathered row for fwd list (by dst)
    int bb = (unsigned)d >> 13;   // bucket of gathered row for bwd list (by src)
    unsigned rf = (unsigned)atomicAdd(&cin_p[(size_t)d * 16 + bf], 1);
    unsigned rb = (unsigned)atomicAdd(&cout_p[(size_t)s * 16 + bb], 1);
    rank_pk[e] = (rf & 0xFFFFu) | (rb << 16);
  } else {                     // conv role
    int cb = blk - blk / 3 - 1;
    int idx = cb * 256 + threadIdx.x;  // over n*32 float4s
    if (idx >= n * 32) return;
    float4 xv = ((const float4*)x)[idx];
    unsigned u0 = (unsigned)f2bf(xv.x) | ((unsigned)f2bf(xv.y) << 16);
    unsigned u1 = (unsigned)f2bf(xv.z) | ((unsigned)f2bf(xv.w) << 16);
    ((uint2*)xbu)[idx] = make_uint2(u0, u1);
  }
}

// Compact + scan-partials + rec deg/prefix fields.
// rec line (16 u32): [0]=offf [1]=degs [2..5]=basef p12,p34,p56,p7 [6,7]=pad
//                    [8]=offb [9]=degs [10..13]=baseb [14,15]=pad
__global__ __launch_bounds__(256) void k_compact_part(const int* __restrict__ cin_p,
                                                      const int* __restrict__ cout_p,
                                                      int* __restrict__ cin_d,
                                                      int* __restrict__ cout_d,
                                                      unsigned* __restrict__ rec,
                                                      int* __restrict__ partA,
                                                      int* __restrict__ partB, int n) {
  __shared__ int redA[256], redB[256];
  int t = threadIdx.x;
  int base = blockIdx.x * 2048 + t * 8;
  int sA = 0, sB = 0;
#pragma unroll
  for (int k = 0; k < 8; ++k) {
    int i = base + k;
    if (i < n) {
      unsigned cinv, coutv;
      unsigned f12, f34, f56, f7;
      {
        const int* pf = &cin_p[(size_t)i * 16];
        int c0 = pf[0], c1 = pf[1], c2 = pf[2], c3 = pf[3];
        int c4 = pf[4], c5 = pf[5], c6 = pf[6], c7 = pf[7];
        unsigned run = c0;
        unsigned p1 = run; run += c1; unsigned p2 = run; run += c2;
        unsigned p3 = run; run += c3; unsigned p4 = run; run += c4;
        unsigned p5 = run; run += c5; unsigned p6 = run; run += c6;
        unsigned p7 = run; run += c7;
        cin_d[i] = (int)run;
        sA += (int)run;
        cinv = (run > 65535u) ? 65535u : run;
        f12 = p1 | (p2 << 16); f34 = p3 | (p4 << 16);
        f56 = p5 | (p6 << 16); f7 = p7;
      }
      unsigned b12, b34, b56, b7;
      {
        const int* pf = &cout_p[(size_t)i * 16];
        int c0 = pf[0], c1 = pf[1], c2 = pf[2], c3 = pf[3];
        int c4 = pf[4], c5 = pf[5], c6 = pf[6], c7 = pf[7];
        unsigned run = c0;
        unsigned p1 = run; run += c1; unsigned p2 = run; run += c2;
        unsigned p3 = run; run += c3; unsigned p4 = run; run += c4;
        unsigned p5 = run; run += c5; unsigned p6 = run; run += c6;
        unsigned p7 = run; run += c7;
        cout_d[i] = (int)run;
        sB += (int)run;
        coutv = (run > 65535u) ? 65535u : run;
        b12 = p1 | (p2 << 16); b34 = p3 | (p4 << 16);
        b56 = p5 | (p6 << 16); b7 = p7;
      }
      unsigned degs = cinv | (coutv << 16);
      unsigned* r = &rec[(size_t)i * 16];
      r[1] = degs; r[2] = f12; r[3] = f34; r[4] = f56; r[5] = f7;
      r[9] = degs; r[10] = b12; r[11] = b34; r[12] = b56; r[13] = b7;
    }
  }
  redA[t] = sA; redB[t] = sB;
  __syncthreads();
  for (int o = 128; o > 0; o >>= 1) {
    if (t < o) { redA[t] += redA[t + o]; redB[t] += redB[t + o]; }
    __syncthreads();
  }
  if (t == 0) { partA[blockIdx.x] = redA[0]; partB[blockIdx.x] = redB[0]; }
}

__global__ __launch_bounds__(64) void k_scan_tops(int* __restrict__ partA,
                                                  int* __restrict__ partB, int nb) {
  int* part = blockIdx.y ? partB : partA;
  if (threadIdx.x == 0) {
    int run = 0;
    for (int i = 0; i < nb; ++i) { int v = part[i]; part[i] = run; run += v; }
  }
}

// Scan output: dense off arrays (for agg) + off fields in rec (for fill).
__global__ __launch_bounds__(256) void k_scan_out(const int* __restrict__ cntA,
                                                  const int* __restrict__ cntB,
                                                  const int* __restrict__ partA,
                                                  const int* __restrict__ partB,
                                                  int* __restrict__ offA,
                                                  int* __restrict__ offB,
                                                  unsigned* __restrict__ rec, int n) {
  const int* cnt = blockIdx.y ? cntB : cntA;
  const int* part = blockIdx.y ? partB : partA;
  int* off = blockIdx.y ? offB : offA;
  int fld = blockIdx.y ? 8 : 0;   // rec word for this direction's off
  __shared__ int ts[256];
  int t = threadIdx.x;
  int base = blockIdx.x * 2048 + t * 8;
  int v[8];
  int s = 0;
#pragma unroll
  for (int i = 0; i < 8; ++i) {
    int idx = base + i;
    int c = (idx < n) ? cnt[idx] : 0;
    v[i] = s;          // exclusive prefix within thread
    s += c;
  }
  ts[t] = s;
  __syncthreads();
  for (int o = 1; o < 256; o <<= 1) {
    int val = (t >= o) ? ts[t - o] : 0;
    __syncthreads();
    ts[t] += val;
    __syncthreads();
  }
  int blockbase = part[blockIdx.x] + (t ? ts[t - 1] : 0);
#pragma unroll
  for (int i = 0; i < 8; ++i) {
    int idx = base + i;
    if (idx <= n) {
      int val = blockbase + v[i];
      off[idx] = val;   // idx==n writes the total
      if (idx < n) rec[(size_t)idx * 16 + fld] = (unsigned)val;
    }
  }
}

// Atomic-free fill; 2 random 64B line touches per edge (rec[d], rec[s]).
__global__ __launch_bounds__(256) void k_fill(const int* __restrict__ src,
                                              const int* __restrict__ dst,
                                              const unsigned* __restrict__ rank_pk,
                                              const uint4* __restrict__ rec4,
                                              unsigned* __restrict__ epf,
                                              unsigned* __restrict__ epb, int E) {
  int e = blockIdx.x * 256 + threadIdx.x;
  if (e >= E) return;
  int s = src[e], d = dst[e];
  unsigned rp = rank_pk[e];
  int rf = (int)(rp & 0xFFFFu), rb = (int)(rp >> 16);
  int bf = (unsigned)s >> 13, bb = (unsigned)d >> 13;
  uint4 f0 = rec4[(size_t)d * 4 + 0];
  uint4 f1 = rec4[(size_t)d * 4 + 1];
  uint4 b0 = rec4[(size_t)s * 4 + 2];
  uint4 b1 = rec4[(size_t)s * 4 + 3];
  unsigned co = b0.y >> 16;       // cout of s (fwd weight deg)
  unsigned ci = f0.y & 0xFFFFu;   // cin of d (bwd weight deg)
  unsigned pf = pre8(f0.z, f0.w, f1.x, f1.y, bf);
  unsigned pb = pre8(b0.z, b0.w, b1.x, b1.y, bb);
  epf[f0.x + pf + (unsigned)rf] = ((unsigned)s << 16) | co;
  epb[b0.x + pb + (unsigned)rb] = ((unsigned)d << 16) | ci;
}

// Fused aggregation + GEMM. Block = 32 nodes, 512 threads (8 waves).
// Agg: waves 0-3 fwd, 4-7 bwd; each 16-lane slot handles 2 nodes (passes
// p=0,1 -> local, local+16). LDS A-tile [32 rows][49 uint4]: cols 0-15 xbu,
// 16-31 fwd, 32-47 bwd, 48 pad. After barrier: wave w computes n-tile nt=w
// for BOTH 16-row M-tiles, loading W (frag-major, L2-resident) once per kc
// into regs and reusing across the 2 M-tiles (halves W L2 traffic).
__global__ __launch_bounds__(512) void k_fused(const uint4* __restrict__ xb,
                                               const int* __restrict__ offA,
                                               const unsigned* __restrict__ epA,
                                               const int* __restrict__ offB,
                                               const unsigned* __restrict__ epB,
                                               const uint4* __restrict__ Whf,
                                               const uint4* __restrict__ Wlf,
                                               const float* __restrict__ bias,
                                               unsigned short* __restrict__ outb,
                                               float* __restrict__ outf, int n) {
  __shared__ uint4 sA[32 * 49];   // 25088 B
  int tid = threadIdx.x;
  int w = tid >> 6, lane = tid & 63;
  int gi = lane >> 4, c = lane & 15;
  int blk = blockIdx.x;
  bool isFwd = w < 4;
  const int* off = isFwd ? offA : offB;
  const unsigned* ep = isFwd ? epA : epB;

  // stage this block's 32 xbu rows (A cols 0..15): 512 threads, 1 uint4 each
  {
    int r = tid >> 4, col = tid & 15;
    int v = blk * 32 + r;
    sA[r * 49 + col] = (v < n) ? xb[(size_t)v * 16 + col]
                               : make_uint4(0u, 0u, 0u, 0u);
  }

#define AGG_BODY(r_, w_)                                                      \
  acc[0] = fmaf(bflo(r_.x), w_, acc[0]); acc[1] = fmaf(bfhi(r_.x), w_, acc[1]); \
  acc[2] = fmaf(bflo(r_.y), w_, acc[2]); acc[3] = fmaf(bfhi(r_.y), w_, acc[3]); \
  acc[4] = fmaf(bflo(r_.z), w_, acc[4]); acc[5] = fmaf(bfhi(r_.z), w_, acc[5]); \
  acc[6] = fmaf(bflo(r_.w), w_, acc[6]); acc[7] = fmaf(bfhi(r_.w), w_, acc[7]);

  // aggregation: 2 sequential node passes per 16-lane slot
#pragma unroll
  for (int p = 0; p < 2; ++p) {
    int local = (w & 3) * 4 + gi + p * 16;   // 0..31
    int node = blk * 32 + local;
    int i = 0, end = 0;
    if (node < n) { i = off[node]; end = off[node + 1]; }
    float acc[8];
#pragma unroll
    for (int k = 0; k < 8; ++k) acc[k] = 0.f;

    for (; i + 3 < end; i += 4) {
      unsigned e0 = ep[i], e1 = ep[i + 1], e2 = ep[i + 2], e3 = ep[i + 3];
      uint4 r0 = xb[(size_t)(e0 >> 16) * 16 + c];
      uint4 r1 = xb[(size_t)(e1 >> 16) * 16 + c];
      uint4 r2 = xb[(size_t)(e2 >> 16) * 16 + c];
      uint4 r3 = xb[(size_t)(e3 >> 16) * 16 + c];
      float w0 = 1.0f / (float)(e0 & 0xFFFFu);   // IEEE div: bit-exact
      float w1 = 1.0f / (float)(e1 & 0xFFFFu);
      float w2 = 1.0f / (float)(e2 & 0xFFFFu);
      float w3 = 1.0f / (float)(e3 & 0xFFFFu);
      AGG_BODY(r0, w0)
      AGG_BODY(r1, w1)
      AGG_BODY(r2, w2)
      AGG_BODY(r3, w3)
    }
    for (; i < end; ++i) {
      unsigned e0 = ep[i];
      uint4 r0 = xb[(size_t)(e0 >> 16) * 16 + c];
      float w0 = 1.0f / (float)(e0 & 0xFFFFu);
      AGG_BODY(r0, w0)
    }

    uint4 o;
    o.x = (unsigned)f2bf(acc[0]) | ((unsigned)f2bf(acc[1]) << 16);
    o.y = (unsigned)f2bf(acc[2]) | ((unsigned)f2bf(acc[3]) << 16);
    o.z = (unsigned)f2bf(acc[4]) | ((unsigned)f2bf(acc[5]) << 16);
    o.w = (unsigned)f2bf(acc[6]) | ((unsigned)f2bf(acc[7]) << 16);
    sA[local * 49 + (isFwd ? 16 : 32) + c] = o;  // A cols 16-31 fwd / 32-47 bwd
  }
#undef AGG_BODY
  __syncthreads();

  // GEMM phase: wave w -> n-tile nt = w, both M-tiles, W loaded once per kc
  int nt = w;
  int lr = lane & 15, q = lane >> 4;
  f32x4 c0 = (f32x4){0.f, 0.f, 0.f, 0.f};
  f32x4 c1 = (f32x4){0.f, 0.f, 0.f, 0.f};
  for (int kc = 0; kc < 12; ++kc) {
    size_t wi = (size_t)((kc * 8 + nt) * 64 + lane);
    bf16x8 bh = as_bf16x8(Whf[wi]);
    bf16x8 bl = as_bf16x8(Wlf[wi]);
    bf16x8 a0 = as_bf16x8(sA[(0 * 16 + lr) * 49 + kc * 4 + q]);
    bf16x8 a1 = as_bf16x8(sA[(1 * 16 + lr) * 49 + kc * 4 + q]);
    c0 = __builtin_amdgcn_mfma_f32_16x16x32_bf16(a0, bh, c0, 0, 0, 0);
    c0 = __builtin_amdgcn_mfma_f32_16x16x32_bf16(a0, bl, c0, 0, 0, 0);
    c1 = __builtin_amdgcn_mfma_f32_16x16x32_bf16(a1, bh, c1, 0, 0, 0);
    c1 = __builtin_amdgcn_mfma_f32_16x16x32_bf16(a1, bl, c1, 0, 0, 0);
  }

  // Epilogue. C layout: col = lane&15, row = (lane>>4)*4 + reg (m89-verified)
  float bv = bias[nt * 16 + lr];
  int colg = nt * 16 + lr;
#pragma unroll
  for (int mt = 0; mt < 2; ++mt) {
    f32x4 cc = mt ? c1 : c0;
#pragma unroll
    for (int reg = 0; reg < 4; ++reg) {
      int row = blk * 32 + mt * 16 + q * 4 + reg;
      if (row >= n) continue;
      if (outb) {
        float t = fmaxf(cc[reg] + bv, 0.f);
        outb[(size_t)row * 128 + colg] = f2bf(t);
      } else {
        outf[(size_t)row * 128 + colg] = cc[reg] + bv;
      }
    }
  }
}

extern "C" void kernel_launch(void* const* d_in, const int* in_sizes, int n_in,
                              void* d_out, int out_size, void* d_ws, size_t ws_size,
                              hipStream_t stream) {
  const int D = 128;
  const int N = in_sizes[0] / D;
  const int E = in_sizes[7];

  const float* x  = (const float*)d_in[0];
  const float* W0 = (const float*)d_in[1];
  const float* b0 = (const float*)d_in[2];
  const float* W1 = (const float*)d_in[3];
  const float* b1 = (const float*)d_in[4];
  const float* W2 = (const float*)d_in[5];
  const float* b2 = (const float*)d_in[6];
  const int* src  = (const int*)d_in[7];
  const int* dst  = (const int*)d_in[8];
  float* out = (float*)d_out;

  char* p = (char*)d_ws;
  auto alloc = [&](size_t bytes) -> char* {
    char* r = p;
    p += (bytes + 15) & ~(size_t)15;
    return r;
  };
  int* cin_p  = (int*)alloc((size_t)N * 64);   // padded: 8 bucket slots / 64B line
  int* cout_p = (int*)alloc((size_t)N * 64);
  int* cin_d  = (int*)alloc((size_t)N * 4);    // dense totals for scan
  int* cout_d = (int*)alloc((size_t)N * 4);
  int* offf = (int*)alloc((size_t)(N + 1) * 4);
  int* offb = (int*)alloc((size_t)(N + 1) * 4);
  unsigned* rec = (unsigned*)alloc((size_t)N * 64);  // 64B fill record / node
  unsigned* rank_pk = (unsigned*)alloc((size_t)E * 4);   // rankf | rankb<<16
  unsigned* epf = (unsigned*)alloc((size_t)E * 4);       // (u<<16 | deg) payload
  unsigned* epb = (unsigned*)alloc((size_t)E * 4);
  unsigned* xbuA = (unsigned*)alloc((size_t)N * 64 * 4); // double-buffered bf16 x
  unsigned* xbuB = (unsigned*)alloc((size_t)N * 64 * 4);
  uint4* Whf[3], *Wlf[3];                     // fragment-major split-bf16 W
  for (int l = 0; l < 3; ++l) {
    Whf[l] = (uint4*)alloc((size_t)12 * 8 * 64 * 16);
    Wlf[l] = (uint4*)alloc((size_t)12 * 8 * 64 * 16);
  }
  int nbScan = (N + 1 + 2047) / 2048;
  int* partA = (int*)alloc((size_t)(nbScan + 1) * 4);
  int* partB = (int*)alloc((size_t)(nbScan + 1) * 4);

  hipMemsetAsync(cin_p, 0, (size_t)2 * N * 64, stream);  // cin_p+cout_p contiguous

  int edgeBlocks = (E + 255) / 256;
  int convBlocks = (N * 32 + 255) / 256;
  int wBase = edgeBlocks + convBlocks + 2;   // edge+conv interleave region
  int fusedBlocks = wBase + 72;              // + 3x24 frag-major wconv blocks
  k_front<<<fusedBlocks, 256, 0, stream>>>(src, dst, cin_p, cout_p, rank_pk,
                                           E, wBase, x, xbuA, N,
                                           W0, W1, W2,
                                           Whf[0], Whf[1], Whf[2],
                                           Wlf[0], Wlf[1], Wlf[2]);
  k_compact_part<<<nbScan, 256, 0, stream>>>(cin_p, cout_p, cin_d, cout_d,
                                             rec, partA, partB, N);
  k_scan_tops<<<dim3(1, 2), 64, 0, stream>>>(partA, partB, nbScan);
  k_scan_out<<<dim3(nbScan, 2), 256, 0, stream>>>(cin_d, cout_d, partA, partB,
                                                  offf, offb, rec, N);
  k_fill<<<(E + 255) / 256, 256, 0, stream>>>(src, dst, rank_pk,
                                              (const uint4*)rec, epf, epb, E);

  const float* bs[3] = {b0, b1, b2};
  int fuseBlocks = (N + 31) / 32;   // 32 nodes/block, 512 threads

  // layer 0: xbuA -> xbuB ; layer 1: xbuB -> xbuA ; layer 2: xbuA -> out(fp32)
  k_fused<<<fuseBlocks, 512, 0, stream>>>(
      (const uint4*)xbuA, offf, epf, offb, epb, Whf[0], Wlf[0], bs[0],
      (unsigned short*)xbuB, nullptr, N);
  k_fused<<<fuseBlocks, 512, 0, stream>>>(
      (const uint4*)xbuB, offf, epf, offb, epb, Whf[1], Wlf[1], bs[1],
      (unsigned short*)xbuA, nullptr, N);
  k_fused<<<fuseBlocks, 512, 0, stream>>>(
      (const uint4*)xbuA, offf, epf, offb, epb, Whf[2], Wlf[2], bs[2],
      nullptr, out, N);
}